// Round 5
// baseline (368.560 us; speedup 1.0000x reference)
//
#include <hip/hip_runtime.h>
#include <cfloat>
#include <cstdint>

#define NPTS 65536
#define DIM 256
#define NC 16
#define KSEL 2048
#define SORT_M 8192
#define EPSV 1e-6f

// ws layout (bytes):
//     0 : float sums[16*256]   (16384)
// 16384 : int counts[16]       (64)
// 16448 : int cursors[16]      (64)
// 16512 : int offsets[16]      (64)
// 16576 : float csq[16]        (64)
// 16640 : float pos_stat[16]   (64)
// 16704 : float neg_stat[256]  (1024)
// 17728 : float centers[4096]  (16384)
// 65536 : float Dmat[16*65536] (4 MB)

__global__ void __launch_bounds__(256) k_accum(const float* __restrict__ x,
                                               const int* __restrict__ y,
                                               float* __restrict__ gsums,
                                               int* __restrict__ gcounts) {
  __shared__ float lsum[NC * DIM];
  __shared__ int lcnt[NC];
  int tid = threadIdx.x;  // = dim
  for (int j = tid; j < NC * DIM; j += 256) lsum[j] = 0.f;
  if (tid < NC) lcnt[tid] = 0;
  __syncthreads();
  int n0 = blockIdx.x * 64;
  for (int r = 0; r < 64; ++r) {
    int n = n0 + r;
    int lab = y[n * 3 + 2];
    lsum[lab * DIM + tid] += x[(size_t)n * DIM + tid];
    if (tid == 0) lcnt[lab]++;
  }
  __syncthreads();
  for (int c = 0; c < NC; ++c)
    atomicAdd(&gsums[c * DIM + tid], lsum[c * DIM + tid]);
  if (tid < NC) atomicAdd(&gcounts[tid], lcnt[tid]);
}

__global__ void __launch_bounds__(256) k_centers(const float* __restrict__ gsums,
                                                 const int* __restrict__ gcounts,
                                                 float* __restrict__ centers,
                                                 float* __restrict__ csq,
                                                 int* __restrict__ offsets) {
  __shared__ float red[DIM];
  int d = threadIdx.x;
  float v[NC];
#pragma unroll
  for (int c = 0; c < NC; ++c) {
    v[c] = gsums[c * DIM + d] / (float)gcounts[c] + EPSV;
    centers[c * DIM + d] = v[c];
  }
#pragma unroll 1
  for (int c = 0; c < NC; ++c) {
    red[d] = v[c] * v[c];
    __syncthreads();
    for (int st = 128; st > 0; st >>= 1) {
      if (d < st) red[d] += red[d + st];
      __syncthreads();
    }
    if (d == 0) csq[c] = red[0];
    __syncthreads();
  }
  if (d == 0) {
    int run = 0;
    for (int c = 0; c < NC; ++c) { offsets[c] = run; run += gcounts[c]; }
  }
}

__global__ void __launch_bounds__(256) k_dist(const float* __restrict__ x,
                                              const int* __restrict__ y,
                                              const float* __restrict__ centers,
                                              const float* __restrict__ csq,
                                              const int* __restrict__ offsets,
                                              int* __restrict__ cursors,
                                              float* __restrict__ Dmat) {
  __shared__ float4 cc[NC * 64];  // 16 centers x 256 dims
  __shared__ float csql[NC];
  int t = threadIdx.x;
  const float4* cptr = (const float4*)centers;
  for (int j = t; j < NC * 64; j += 256) cc[j] = cptr[j];
  if (t < NC) csql[t] = csq[t];
  __syncthreads();

  int n = blockIdx.x * 256 + t;
  const float4* xp = (const float4*)(x + (size_t)n * DIM);
  float acc[NC];
#pragma unroll
  for (int i = 0; i < NC; ++i) acc[i] = 0.f;
  float xsq = 0.f;
  for (int q = 0; q < 64; ++q) {
    float4 xv = xp[q];
    xsq += xv.x * xv.x + xv.y * xv.y + xv.z * xv.z + xv.w * xv.w;
#pragma unroll
    for (int i = 0; i < NC; ++i) {
      float4 cv = cc[i * 64 + q];
      acc[i] += xv.x * cv.x + xv.y * cv.y + xv.z * cv.z + xv.w * cv.w;
    }
  }
  int lab = y[n * 3 + 2];
  int slot = atomicAdd(&cursors[lab], 1);
  int base = offsets[lab] + slot;
#pragma unroll
  for (int i = 0; i < NC; ++i) {
    float d2 = csql[i] - 2.f * acc[i] + xsq;
    Dmat[(size_t)i * NPTS + base] = sqrtf(fmaxf(d2, 0.f));
  }
}

__global__ void __launch_bounds__(512) k_select(const float* __restrict__ Dmat,
                                                const int* __restrict__ gcounts,
                                                const int* __restrict__ offsets,
                                                float* __restrict__ pos_stat,
                                                float* __restrict__ neg_stat) {
  __shared__ float s[SORT_M];
  __shared__ float red[512];
  int tid = threadIdx.x;
  int b = blockIdx.x;
  int ci = b >> 4;  // center index i
  int cl = b & 15;  // class index c
  int cnt = gcounts[cl];
  int off = offsets[cl];
  const float* src = Dmat + (size_t)ci * NPTS + off;
  for (int t = tid; t < SORT_M; t += 512) s[t] = (t < cnt) ? src[t] : FLT_MAX;
  __syncthreads();

  for (int k = 2; k <= SORT_M; k <<= 1) {
    for (int j = k >> 1; j > 0; j >>= 1) {
      for (int p = tid; p < SORT_M / 2; p += 512) {
        int i = ((p & ~(j - 1)) << 1) | (p & (j - 1));
        int ixj = i | j;
        bool up = ((i & k) == 0);
        float a = s[i], bb = s[ixj];
        if ((a > bb) == up) { s[i] = bb; s[ixj] = a; }
      }
      __syncthreads();
    }
  }

  // --- neg stats: K smallest = s[0..KSEL) ---
  float part = 0.f;
  for (int t = tid; t < KSEL; t += 512) part += s[t];
  red[tid] = part; __syncthreads();
  for (int st = 256; st > 0; st >>= 1) { if (tid < st) red[tid] += red[tid + st]; __syncthreads(); }
  float mean = red[0] / (float)KSEL;
  __syncthreads();
  part = 0.f;
  for (int t = tid; t < KSEL; t += 512) { float dd = s[t] - mean; part += dd * dd; }
  red[tid] = part; __syncthreads();
  for (int st = 256; st > 0; st >>= 1) { if (tid < st) red[tid] += red[tid + st]; __syncthreads(); }
  if (tid == 0) {
    float var = red[0] / (float)(KSEL - 1);
    neg_stat[ci * 16 + cl] = mean - 1.96f * sqrtf(var);
  }

  // --- pos stats (only diagonal): K largest = s[cnt-KSEL..cnt) ---
  if (ci == cl) {
    __syncthreads();
    part = 0.f;
    for (int t = tid; t < KSEL; t += 512) part += s[cnt - KSEL + t];
    red[tid] = part; __syncthreads();
    for (int st = 256; st > 0; st >>= 1) { if (tid < st) red[tid] += red[tid + st]; __syncthreads(); }
    float pm = red[0] / (float)KSEL;
    __syncthreads();
    part = 0.f;
    for (int t = tid; t < KSEL; t += 512) { float dd = s[cnt - KSEL + t] - pm; part += dd * dd; }
    red[tid] = part; __syncthreads();
    for (int st = 256; st > 0; st >>= 1) { if (tid < st) red[tid] += red[tid + st]; __syncthreads(); }
    if (tid == 0) {
      float var = red[0] / (float)(KSEL - 1);
      pos_stat[ci] = pm + 1.96f * sqrtf(var);
    }
  }
}

__global__ void __launch_bounds__(256) k_loss(const float* __restrict__ pos_stat,
                                              const float* __restrict__ neg_stat,
                                              float* __restrict__ out) {
  __shared__ float red[256];
  int t = threadIdx.x;
  int i = t >> 4, c = t & 15;
  float v = 0.f;
  if (i != c) v = fmaxf(1.0f + pos_stat[i] - neg_stat[t], 0.f);
  red[t] = v; __syncthreads();
  for (int st = 128; st > 0; st >>= 1) { if (t < st) red[t] += red[t + st]; __syncthreads(); }
  if (t == 0) out[0] = red[0];
}

extern "C" void kernel_launch(void* const* d_in, const int* in_sizes, int n_in,
                              void* d_out, int out_size, void* d_ws, size_t ws_size,
                              hipStream_t stream) {
  const float* x = (const float*)d_in[0];
  const int* y = (const int*)d_in[1];
  float* out = (float*)d_out;
  char* ws = (char*)d_ws;

  float* sums = (float*)(ws + 0);
  int* counts = (int*)(ws + 16384);
  int* cursors = (int*)(ws + 16448);
  int* offsets = (int*)(ws + 16512);
  float* csq = (float*)(ws + 16576);
  float* pos_stat = (float*)(ws + 16640);
  float* neg_stat = (float*)(ws + 16704);
  float* centers = (float*)(ws + 17728);
  float* Dmat = (float*)(ws + 65536);

  hipMemsetAsync(ws, 0, 16512, stream);  // sums + counts + cursors
  k_accum<<<1024, 256, 0, stream>>>(x, y, sums, counts);
  k_centers<<<1, 256, 0, stream>>>(sums, counts, centers, csq, offsets);
  k_dist<<<256, 256, 0, stream>>>(x, y, centers, csq, offsets, cursors, Dmat);
  k_select<<<256, 512, 0, stream>>>(Dmat, counts, offsets, pos_stat, neg_stat);
  k_loss<<<1, 256, 0, stream>>>(pos_stat, neg_stat, out);
}